// Round 11
// baseline (341.876 us; speedup 1.0000x reference)
//
#include <hip/hip_runtime.h>

// Physics_Attention_Irregular_Mesh — round 12
// B=4, N=16384, DIM=256, H=8, D=64, G=32, inner=512. f32 I/O.
// r12 (r11 post-mortem: 16 SEPARATE "+v" pins sank one-by-one into the MFMA
// loop in order — VGPR 48->52, one frag pinned, same 94us):
//  1. ONE 16-operand asm pin: all frags are operands of a single statement,
//     so all 64 VGPRs are simultaneously live and unsinkable/unsplittable.
//  2. Coalesced interleaved A-staging: thread t loads 16B at t*16+j*8192
//     (lane-contiguous per instr, 4x fewer L1 transactions than the old
//     stride-64B pattern) + ds_write_b64/b128 swizzled.
// Applied to kproj AND kout. k4 / k4b / k5 / kZ / preps unchanged.

typedef unsigned short u16;
typedef __attribute__((ext_vector_type(8))) unsigned short ushort8v;
typedef __attribute__((ext_vector_type(4))) unsigned short ushort4v;
typedef __attribute__((ext_vector_type(8))) short short8v;
typedef __attribute__((ext_vector_type(4))) float f32x4;

constexpr int Nc = 16384;
constexpr int BNc = 65536;

__device__ inline float b2f(u16 v) {
    union { unsigned int u; float f; } t; t.u = ((unsigned int)v) << 16; return t.f;
}
__device__ inline u16 f2b(float f) {   // round-to-nearest-even
    union { float f; unsigned int u; } t; t.f = f;
    unsigned int u = t.u;
    return (u16)((u + 0x7fffu + ((u >> 16) & 1u)) >> 16);
}

// Atomic 16-fragment pin: single asm statement, all fragments are
// read-write operands -> 64 VGPRs simultaneously live, no remat after.
#define PIN16(a, b)                                                          \
    asm volatile("" :                                                        \
        "+v"((a)[0]), "+v"((a)[1]), "+v"((a)[2]), "+v"((a)[3]),              \
        "+v"((a)[4]), "+v"((a)[5]), "+v"((a)[6]), "+v"((a)[7]),              \
        "+v"((b)[0]), "+v"((b)[1]), "+v"((b)[2]), "+v"((b)[3]),              \
        "+v"((b)[4]), "+v"((b)[5]), "+v"((b)[6]), "+v"((b)[7]))

// ---------------- prep: fold WxsT[h*32+g][k] = (Wx_h @ Wslice)^T, bxs ------
__global__ __launch_bounds__(256) void k0_fold(
    const float* __restrict__ Wx, const float* __restrict__ Wslice,
    const float* __restrict__ bx, const float* __restrict__ bslice,
    u16* __restrict__ WxsT, float* __restrict__ bxs)
{
    int blk = blockIdx.x, tid = threadIdx.x;
    int h = tid >> 5, g = tid & 31;
    if (blk < 256) {
        int k = blk;
        float acc = 0.f;
        for (int d = 0; d < 64; d++)
            acc += Wx[k * 512 + h * 64 + d] * Wslice[d * 32 + g];
        WxsT[tid * 256 + k] = f2b(acc);
    } else {
        float acc = 0.f;
        for (int d = 0; d < 64; d++)
            acc += bx[h * 64 + d] * Wslice[d * 32 + g];
        bxs[tid] = acc + bslice[g];
    }
}

// ---------------- prep: WfxT[n][k] bf16 ----------------
__global__ __launch_bounds__(256) void kprep_wfx(const float* __restrict__ Wfx,
                                                 u16* __restrict__ WfxT)
{
    int n = blockIdx.x, k = threadIdx.x;        // 512 blocks x 256
    WfxT[n * 256 + k] = f2b(Wfx[k * 512 + n]);
}

// ---------------- kfrag: repack Ball -> chunk-major fragment order --------
__global__ __launch_bounds__(256) void kfrag(const u16* __restrict__ Ball,
                                             u16* __restrict__ Bf)
{
    int g = blockIdx.x * 256 + threadIdx.x;   // 96 blocks -> 24576 threads
    int pair = g >> 6, lane = g & 63;
    int t = pair >> 3, c = pair & 7;
    int n = t * 16 + (lane & 15);
    int k = c * 32 + (lane >> 4) * 8;
    ushort8v v = *(const ushort8v*)(Ball + (size_t)n * 256 + k);
    *(ushort8v*)(Bf + (size_t)((c * 48 + t) * 64 + lane) * 8) = v;
}

// ---------------- kproj: fused projection, barrier-free (B in regs) -------
// Grid (2048, 3) x 512. Block = 32 rows x 16 tiles (tile-group tg).
// Wave q owns tiles {tg*16+2q, tg*16+2q+1} x 32 rows (2 row-frags).
// B: 16 frags in VGPRs, loaded once, pinned by ONE 16-operand asm.
// A: 32x256 bf16 in LDS, XOR-swizzled rows, coalesced interleaved staging.
// Inner: 8 chunks x {2 ds_read_b128 (A, broadcast) + 4 MFMA}. One barrier.
__global__ __launch_bounds__(512, 4) void kproj(
    const float* __restrict__ x, const u16* __restrict__ Bf,
    const float* __restrict__ bfx, const float* __restrict__ bxs,
    const float* __restrict__ temp,
    u16* __restrict__ fxT, u16* __restrict__ swb, u16* __restrict__ swT)
{
    __shared__ u16 As[32 * 256];   // 16 KiB bf16, row-XOR-swizzled
    int tid = threadIdx.x;
    int wave = tid >> 6, lane = tid & 63;
    int lm = lane & 15, quad = lane >> 4;
    int tg = blockIdx.y;
    int row0 = blockIdx.x * 32;
    int T0 = tg * 16 + 2 * wave;           // wave's tile pair T0, T0+1

    // ---- issue B-frag loads: 16 x 16B/lane, coalesced, L2-resident ----
    short8v breg0[8], breg1[8];
#pragma unroll
    for (int c = 0; c < 8; c++) {
        breg0[c] = *(const short8v*)(Bf + (size_t)((c * 48 + T0) * 64 + lane) * 8);
        breg1[c] = *(const short8v*)(Bf + (size_t)((c * 48 + T0 + 1) * 64 + lane) * 8);
    }

    // ---- stage A: 32 rows x 1024B of x, coalesced interleaved pieces ----
    // thread t, piece j: 16B at tile byte t*16 + j*8192 (lane-contiguous
    // per instruction). Tile is contiguous in x (row stride 1024B).
    {
        const char* xb = (const char*)(x + (size_t)row0 * 256);
#pragma unroll
        for (int j = 0; j < 4; j++) {
            int g = tid * 16 + j * 8192;
            f32x4 v = *(const f32x4*)(xb + g);
            ushort4v o;
#pragma unroll
            for (int k = 0; k < 4; k++) o[k] = f2b(v[k]);
            int row = g >> 10, bcol = (g & 1023) >> 1;   // bf16 byte col, mult of 8
            char* dst = (char*)As + row * 512 + (bcol ^ ((row & 7) << 4));
            *(ushort4v*)dst = o;   // ds_write_b64
        }
    }

    // ---- atomic pin: whole B-panel materialized in VGPRs here ----
    PIN16(breg0, breg1);

    __syncthreads();               // the ONLY barrier

    // ---- main: 8 chunks x {2 A ds_reads + 4 MFMA}, B from regs ----
    f32x4 acc00 = {}, acc01 = {}, acc10 = {}, acc11 = {};
    int swl = (lm & 7) << 4;
    const char* Arow0 = (const char*)As + lm * 512;          // rf=0 row
    const char* Arow1 = (const char*)As + (16 + lm) * 512;   // rf=1 row
#pragma unroll
    for (int c = 0; c < 8; c++) {
        int off = (c * 64 + quad * 16) ^ swl;
        short8v af0 = *(const short8v*)(Arow0 + off);
        short8v af1 = *(const short8v*)(Arow1 + off);
        acc00 = __builtin_amdgcn_mfma_f32_16x16x32_bf16(af0, breg0[c], acc00, 0, 0, 0);
        acc10 = __builtin_amdgcn_mfma_f32_16x16x32_bf16(af1, breg0[c], acc10, 0, 0, 0);
        acc01 = __builtin_amdgcn_mfma_f32_16x16x32_bf16(af0, breg1[c], acc01, 0, 0, 0);
        acc11 = __builtin_amdgcn_mfma_f32_16x16x32_bf16(af1, breg1[c], acc11, 0, 0, 0);
    }

    // ---- epilogue ----
    if (tg < 2) {
        // pure fx tiles
        int nbase = row0 + quad * 4;
#pragma unroll
        for (int i = 0; i < 2; i++) {
            int cc = (T0 + i) * 16 + lm;
            float bv = bfx[cc];
            const f32x4& a0 = i ? acc01 : acc00;
            const f32x4& a1 = i ? acc11 : acc10;
            ushort4v o0, o1;
#pragma unroll
            for (int r = 0; r < 4; r++) { o0[r] = f2b(a0[r] + bv); o1[r] = f2b(a1[r] + bv); }
            *(ushort4v*)(fxT + (size_t)cc * 65536 + nbase) = o0;
            *(ushort4v*)(fxT + (size_t)cc * 65536 + nbase + 16) = o1;
        }
    } else {
        // softmax tiles: wave q = head q; acc*0 -> g=lm, acc*1 -> g=16+lm
        int h = wave;
        int b = row0 >> 14;
        float it = 1.0f / temp[h];
        float bv0 = bxs[h * 32 + lm];
        float bv1 = bxs[h * 32 + 16 + lm];
        size_t gbase = (size_t)((b * 8 + h) * 32);
#pragma unroll
        for (int rf = 0; rf < 2; rf++) {
            const f32x4& A0 = rf ? acc10 : acc00;
            const f32x4& A1 = rf ? acc11 : acc01;
            int nlbase = (row0 & 16383) + rf * 16 + quad * 4;
            ushort4v p0, p1;
#pragma unroll
            for (int r = 0; r < 4; r++) {
                float v0 = (A0[r] + bv0) * it;       // g = lm
                float v1 = (A1[r] + bv1) * it;       // g = 16+lm
                float m = fmaxf(v0, v1);
                m = fmaxf(m, __shfl_xor(m, 1));
                m = fmaxf(m, __shfl_xor(m, 2));
                m = fmaxf(m, __shfl_xor(m, 4));
                m = fmaxf(m, __shfl_xor(m, 8));
                float e0 = __expf(v0 - m), e1 = __expf(v1 - m);
                float s = e0 + e1;
                s += __shfl_xor(s, 1);
                s += __shfl_xor(s, 2);
                s += __shfl_xor(s, 4);
                s += __shfl_xor(s, 8);
                float rs = 1.0f / s;
                float w0 = e0 * rs, w1 = e1 * rs;
                int row = row0 + rf * 16 + quad * 4 + r;
                swb[(size_t)row * 256 + h * 32 + lm] = f2b(w0);
                swb[(size_t)row * 256 + h * 32 + 16 + lm] = f2b(w1);
                p0[r] = f2b(w0); p1[r] = f2b(w1);
            }
            *(ushort4v*)(swT + (gbase + lm) * 16384 + nlbase) = p0;
            *(ushort4v*)(swT + (gbase + 16 + lm) * 16384 + nlbase) = p1;
        }
    }
}

// ---------------- kout: out = swb @ ZTf_b^T + bout, barrier-free ----------
// Same structure as kproj: grid 2048 x 512 thr. Block = 32 rows x 16 tiles;
// wave q owns tiles {2q, 2q+1}. B = ZTf frags pinned (one 16-op asm);
// A = swb staged once to swizzled LDS, coalesced interleaved. ONE barrier.
__global__ __launch_bounds__(512, 4) void kout(
    const u16* __restrict__ swb, const u16* __restrict__ ZTf,
    const float* __restrict__ bout, float* __restrict__ out)
{
    __shared__ u16 As[32 * 256];   // 16 KiB
    int tid = threadIdx.x;
    int wave = tid >> 6, lane = tid & 63;
    int lm = lane & 15, quad = lane >> 4;
    int row0 = blockIdx.x * 32;
    int T0 = 2 * wave;
    int b = row0 >> 14;

    // ---- B-frag loads ----
    const u16* Zb = ZTf + (size_t)b * 65536;
    short8v breg0[8], breg1[8];
#pragma unroll
    for (int c = 0; c < 8; c++) {
        breg0[c] = *(const short8v*)(Zb + (size_t)((c * 16 + T0) * 64 + lane) * 8);
        breg1[c] = *(const short8v*)(Zb + (size_t)((c * 16 + T0 + 1) * 64 + lane) * 8);
    }

    // ---- stage A: swb 32 rows x 512B, coalesced interleaved pieces ----
    {
        const char* sb = (const char*)(swb + (size_t)row0 * 256);
#pragma unroll
        for (int j = 0; j < 2; j++) {
            int g = tid * 16 + j * 8192;
            ushort8v v = *(const ushort8v*)(sb + g);
            int row = g >> 9, colb = g & 511;   // colb mult of 16
            char* dst = (char*)As + row * 512 + (colb ^ ((row & 7) << 4));
            *(ushort8v*)dst = v;   // ds_write_b128
        }
    }

    // ---- atomic pin ----
    PIN16(breg0, breg1);

    __syncthreads();               // the ONLY barrier

    // ---- main loop ----
    f32x4 acc00 = {}, acc01 = {}, acc10 = {}, acc11 = {};
    int swl = (lm & 7) << 4;
    const char* Arow0 = (const char*)As + lm * 512;
    const char* Arow1 = (const char*)As + (16 + lm) * 512;
#pragma unroll
    for (int c = 0; c < 8; c++) {
        int off = (c * 64 + quad * 16) ^ swl;
        short8v af0 = *(const short8v*)(Arow0 + off);
        short8v af1 = *(const short8v*)(Arow1 + off);
        acc00 = __builtin_amdgcn_mfma_f32_16x16x32_bf16(af0, breg0[c], acc00, 0, 0, 0);
        acc10 = __builtin_amdgcn_mfma_f32_16x16x32_bf16(af1, breg0[c], acc10, 0, 0, 0);
        acc01 = __builtin_amdgcn_mfma_f32_16x16x32_bf16(af0, breg1[c], acc01, 0, 0, 0);
        acc11 = __builtin_amdgcn_mfma_f32_16x16x32_bf16(af1, breg1[c], acc11, 0, 0, 0);
    }

    // ---- epilogue: f32 + bias ----
    int cc0 = T0 * 16 + lm, cc1 = cc0 + 16;
    float bv0 = bout[cc0], bv1 = bout[cc1];
#pragma unroll
    for (int r = 0; r < 4; r++) {
        int rowa = row0 + quad * 4 + r;
        int rowb = rowa + 16;
        out[(size_t)rowa * 256 + cc0] = acc00[r] + bv0;
        out[(size_t)rowa * 256 + cc1] = acc01[r] + bv1;
        out[(size_t)rowb * 256 + cc0] = acc10[r] + bv0;
        out[(size_t)rowb * 256 + cc1] = acc11[r] + bv1;
    }
}

// ---------------- k4: token pooling, LDS-staged (swizzled), split-K -------
__global__ __launch_bounds__(256, 4) void k4_token_mfma(
    const u16* __restrict__ swT, const u16* __restrict__ fxT,
    float* __restrict__ token_part, float* __restrict__ norm_part)
{
    __shared__ u16 As[32 * 256];     // 16 KiB
    __shared__ u16 Bs_[64 * 256];    // 32 KiB
    int bh = blockIdx.x, ky = blockIdx.y;
    int b = bh >> 3, h = bh & 7;
    int tid = threadIdx.x, wave = tid >> 6, lane = tid & 63;
    int lm = lane & 15, quad = lane >> 4;
    int mt = wave & 1, dp = wave >> 1;
    int lh = lane >> 5, lb = lane & 31;

#pragma unroll
    for (int i = 0; i < 4; i++) {
        int s = wave * 4 + i;                  // 0..15 -> rows 2s, 2s+1
        int r = 2 * s + lh;
        int sw = ((lb * 16) ^ ((r & 7) << 4)) >> 1;   // u16 offset in row
        const u16* src = swT + (size_t)(bh * 32 + r) * 16384 + ky * 256 + sw;
        __builtin_amdgcn_global_load_lds((const uint32_t*)src,
                                         (uint32_t*)(&As[s * 512]), 16, 0, 0);
    }
#pragma unroll
    for (int i = 0; i < 8; i++) {
        int s = wave * 8 + i;                  // 0..31 -> rows 2s, 2s+1
        int r = 2 * s + lh;
        int sw = ((lb * 16) ^ ((r & 7) << 4)) >> 1;
        const u16* src = fxT + (size_t)(h * 64 + r) * 65536 + (size_t)b * 16384
                         + ky * 256 + sw;
        __builtin_amdgcn_global_load_lds((const uint32_t*)src,
                                         (uint32_t*)(&Bs_[s * 512]), 16, 0, 0);
    }
    __syncthreads();

    int rA = mt * 16 + lm;
    int rB0 = dp * 32 + lm, rB1 = rB0 + 16;
    const char* Ab  = (const char*)As  + rA  * 512;
    const char* Bb0 = (const char*)Bs_ + rB0 * 512;
    const char* Bb1 = (const char*)Bs_ + rB1 * 512;
    int swA  = (rA  & 7) << 4;
    int swB0 = (rB0 & 7) << 4;
    int swB1 = (rB1 & 7) << 4;

    f32x4 acc0 = {}, acc1 = {};
    float nacc = 0.f;
#pragma unroll
    for (int kk = 0; kk < 8; kk++) {
        int base = kk * 64 + quad * 16;
        short8v af = *(const short8v*)(Ab  + (base ^ swA));
        short8v b0 = *(const short8v*)(Bb0 + (base ^ swB0));
        short8v b1 = *(const short8v*)(Bb1 + (base ^ swB1));
        acc0 = __builtin_amdgcn_mfma_f32_16x16x32_bf16(af, b0, acc0, 0, 0, 0);
        acc1 = __builtin_amdgcn_mfma_f32_16x16x32_bf16(af, b1, acc1, 0, 0, 0);
        if (dp == 0) {
            ushort8v au = (ushort8v&)af;
#pragma unroll
            for (int j = 0; j < 8; j++) nacc += b2f(au[j]);
        }
    }
    float* tp = token_part + ((size_t)(ky * 32 + bh)) * 2048;
#pragma unroll
    for (int r = 0; r < 4; r++) {
        int g = mt * 16 + quad * 4 + r;
        tp[g * 64 + dp * 32 + lm] = acc0[r];
        tp[g * 64 + dp * 32 + 16 + lm] = acc1[r];
    }
    if (dp == 0) {
        nacc += __shfl_xor(nacc, 16);
        nacc += __shfl_xor(nacc, 32);
        if (lane < 16)
            norm_part[(ky * 32 + bh) * 32 + mt * 16 + lm] = nacc;
    }
}

// ---------------- k4b: reduce partials -> tl = token/(norm+1e-5) ----------
__global__ __launch_bounds__(256) void k4b_reduce(
    const float* __restrict__ tp, const float* __restrict__ np,
    float* __restrict__ tl)
{
    int t = blockIdx.x * 256 + threadIdx.x;   // 65536
    int bh = t >> 11, e = t & 2047, g = e >> 6;
    float ts = 0.f, ns = 0.f;
    for (int ch = 0; ch < 64; ch++) {
        ts += tp[((size_t)(ch * 32 + bh)) * 2048 + e];
        ns += np[(ch * 32 + bh) * 32 + g];
    }
    tl[t] = ts / (ns + 1e-5f);
}

// ---------------- k5: tiny attention over G tokens ----------------
__global__ __launch_bounds__(256) void k5_attn(
    const float* __restrict__ tlg,
    const float* __restrict__ Wq, const float* __restrict__ Wk, const float* __restrict__ Wv,
    float* __restrict__ out_slice)
{
    __shared__ float tl[32][64];
    __shared__ float ql[32][64], kl[32][64], vl[32][64];
    __shared__ float sl[32][33];
    int bh = blockIdx.x, tid = threadIdx.x;
    const float* tk = tlg + (size_t)bh * 2048;

#pragma unroll
    for (int j = 0; j < 8; j++) {
        int idx = j * 256 + tid;
        tl[idx >> 6][idx & 63] = tk[idx];
    }
    __syncthreads();
#pragma unroll
    for (int j = 0; j < 8; j++) {
        int idx = j * 256 + tid;
        int g = idx >> 6, d = idx & 63;
        float aq = 0.f, ak = 0.f, av = 0.f;
        for (int e = 0; e < 64; e++) {
            float t = tl[g][e];
            aq += t * Wq[e * 64 + d];
            ak += t * Wk[e * 64 + d];
            av += t * Wv[e * 64 + d];
        }
        ql[g][d] = aq; kl[g][d] = ak; vl[g][d] = av;
    }
    __syncthreads();
#pragma unroll
    for (int j = 0; j < 4; j++) {
        int idx = j * 256 + tid;
        int gq = idx >> 5, gk = idx & 31;
        float s = 0.f;
        for (int d = 0; d < 64; d++) s += ql[gq][d] * kl[gk][d];
        sl[gq][gk] = s * 0.125f;   // 1/sqrt(64)
    }
    __syncthreads();
    if (tid < 32) {
        float m = -1e30f;
        for (int k2 = 0; k2 < 32; k2++) m = fmaxf(m, sl[tid][k2]);
        float s = 0.f;
        for (int k2 = 0; k2 < 32; k2++) { float e = __expf(sl[tid][k2] - m); sl[tid][k2] = e; s += e; }
        float r = 1.0f / s;
        for (int k2 = 0; k2 < 32; k2++) sl[tid][k2] *= r;
    }
    __syncthreads();
#pragma unroll
    for (int j = 0; j < 8; j++) {
        int idx = j * 256 + tid;
        int g = idx >> 6, d = idx & 63;
        float a = 0.f;
        for (int k2 = 0; k2 < 32; k2++) a += sl[g][k2] * vl[k2][d];
        out_slice[(size_t)bh * 2048 + idx] = a;
    }
}

// ---------------- kZ: ZTf[b][ch][tile][lane][8] = frag-order (os@Wout)^T --
__global__ __launch_bounds__(256) void kZ(
    const float* __restrict__ os, const float* __restrict__ Wout,
    u16* __restrict__ ZTf)
{
    int b = blockIdx.x, cb = blockIdx.y;   // grid (4, 16)
    int t = threadIdx.x;
    int c = cb * 16 + (t & 15), kq = t >> 4;
    int tile = c >> 4, lm = c & 15;
    for (int k = kq * 16; k < kq * 16 + 16; k++) {
        int h = k >> 5, g = k & 31;
        const float* osr = os + ((size_t)(b * 8 + h)) * 2048 + g * 64;
        float acc = 0.f;
        for (int d = 0; d < 64; d++)
            acc += osr[d] * Wout[(h * 64 + d) * 256 + c];
        int ch = k >> 5, quad = (k >> 3) & 3, jj = k & 7;
        int lane = quad * 16 + lm;
        ZTf[((size_t)((b * 8 + ch) * 16 + tile)) * 512 + lane * 8 + jj] = f2b(acc);
    }
}

// ---------------- launcher ----------------
extern "C" void kernel_launch(void* const* d_in, const int* in_sizes, int n_in,
                              void* d_out, int out_size, void* d_ws, size_t ws_size,
                              hipStream_t stream)
{
    const float* x      = (const float*)d_in[0];
    const float* Wfx    = (const float*)d_in[1];
    const float* bfx    = (const float*)d_in[2];
    const float* Wx     = (const float*)d_in[3];
    const float* bx     = (const float*)d_in[4];
    const float* Wslice = (const float*)d_in[5];
    const float* bslice = (const float*)d_in[6];
    const float* temp   = (const float*)d_in[7];
    const float* Wq     = (const float*)d_in[8];
    const float* Wk     = (const float*)d_in[9];
    const float* Wv     = (const float*)d_in[10];
    const float* Wout   = (const float*)d_in[11];
    const float* bout   = (const float*)d_in[12];

    char* ws = (char*)d_ws;
    size_t off = 0;
    auto alloc = [&](size_t bytes) {
        void* p = ws + off;
        off = (off + bytes + 255) & ~(size_t)255;
        return p;
    };
    u16*   fxT   = (u16*)  alloc((size_t)512 * BNc * 2);   // 64 MiB
    u16*   swb   = (u16*)  alloc((size_t)BNc * 256 * 2);   // 32 MiB
    u16*   swT   = (u16*)  alloc((size_t)1024 * Nc * 2);   // 32 MiB
    float* tp    = (float*)alloc((size_t)2048 * 2048 * 4); // 16 MiB (64 ky x 32 bh)
    float* np    = (float*)alloc((size_t)2048 * 32 * 4);   // 256 KiB
    float* tl    = (float*)alloc(65536 * 4);               // 256 KiB
    float* osl   = (float*)alloc(65536 * 4);               // 256 KiB
    u16*   ZTf   = (u16*)  alloc(4 * 65536 * 2);           // 512 KiB, chunk-major frag order
    u16*   Ball  = (u16*)  alloc((size_t)768 * 256 * 2);   // WfxT rows 0-511, WxsT 512-767
    u16*   Bfrg  = (u16*)  alloc((size_t)768 * 256 * 2);   // chunk-major frag-ordered Ball
    float* bxs   = (float*)alloc(256 * 4);

    u16* WfxT = Ball;
    u16* WxsT = Ball + (size_t)512 * 256;

    k0_fold<<<257, 256, 0, stream>>>(Wx, Wslice, bx, bslice, WxsT, bxs);
    kprep_wfx<<<512, 256, 0, stream>>>(Wfx, WfxT);
    kfrag<<<96, 256, 0, stream>>>(Ball, Bfrg);

    // fused: fxT = (x @ Wfx + bfx)^T  AND  softmax((x @ Wxs + bxs)/T) -> swb, swT
    kproj<<<dim3(2048, 3), 512, 0, stream>>>(x, Bfrg, bfx, bxs, temp, fxT, swb, swT);

    k4_token_mfma<<<dim3(32, 64), 256, 0, stream>>>(swT, fxT, tp, np);
    k4b_reduce<<<256, 256, 0, stream>>>(tp, np, tl);
    k5_attn<<<32, 256, 0, stream>>>(tl, Wq, Wk, Wv, osl);
    kZ<<<dim3(4, 16), 256, 0, stream>>>(osl, Wout, ZTf);

    // out = swb @ ZTf_b^T + bout -> f32 d_out
    kout<<<2048, 512, 0, stream>>>(swb, ZTf, bout, (float*)d_out);
}